// Round 7
// baseline (157.522 us; speedup 1.0000x reference)
//
#include <hip/hip_runtime.h>
#include <cstddef>

#define HH 224
#define WW 608
#define HWSZ (HH * WW)

__device__ __forceinline__ float lrelu(float v) { return v > 0.0f ? v : 0.01f * v; }

// CondMul, output dim split across a 4-lane group (sub-lane s).
// Weight layout [i=0..31][o=0..CO-1] (wmat already offset by the gather index).
// Activations distributed 8/lane; lane sp holds act[ii] = x[8*sp+ii].
// Accumulation: i ascending per output, bias last — matches reference order.
template <int CO>
__device__ __forceinline__ void cm4(const float* __restrict__ wmat,
                                    const float* __restrict__ bvec,
                                    int s, const float (&act)[8], float (&acc)[CO / 4]) {
    constexpr int CH = CO / 4;
#pragma unroll
    for (int j = 0; j < CH; j++) acc[j] = 0.0f;
#pragma unroll
    for (int sp = 0; sp < 4; sp++) {
#pragma unroll
        for (int ii = 0; ii < 8; ii++) {
            float xi = __shfl(act[ii], sp, 4);
            const float* wr = wmat + (sp * 8 + ii) * CO + s * CH;
            if constexpr (CH == 8) {
                float4 a = *reinterpret_cast<const float4*>(wr);
                float4 b = *reinterpret_cast<const float4*>(wr + 4);
                acc[0] = fmaf(xi, a.x, acc[0]); acc[1] = fmaf(xi, a.y, acc[1]);
                acc[2] = fmaf(xi, a.z, acc[2]); acc[3] = fmaf(xi, a.w, acc[3]);
                acc[4] = fmaf(xi, b.x, acc[4]); acc[5] = fmaf(xi, b.y, acc[5]);
                acc[6] = fmaf(xi, b.z, acc[6]); acc[7] = fmaf(xi, b.w, acc[7]);
            } else {
                float4 a = *reinterpret_cast<const float4*>(wr);
                acc[0] = fmaf(xi, a.x, acc[0]); acc[1] = fmaf(xi, a.y, acc[1]);
                acc[2] = fmaf(xi, a.z, acc[2]); acc[3] = fmaf(xi, a.w, acc[3]);
            }
        }
    }
#pragma unroll
    for (int j = 0; j < CH; j++) acc[j] += bvec[s * CH + j];
}

__device__ __forceinline__ void wb_lrelu8(float (&act)[8], const float (&acc)[8]) {
#pragma unroll
    for (int j = 0; j < 8; j++) act[j] = lrelu(acc[j]);
}

// First-max argmax over 16 values distributed 4-per-lane across the 4-lane group.
__device__ __forceinline__ int argmax4(const float (&v)[4], int s) {
    float bv = v[0];
    int bi = 4 * s;
#pragma unroll
    for (int j = 1; j < 4; j++) {
        if (v[j] > bv) { bv = v[j]; bi = 4 * s + j; }
    }
#pragma unroll
    for (int m = 1; m <= 2; m <<= 1) {
        float ov = __shfl_xor(bv, m, 4);
        int oi = __shfl_xor(bi, m, 4);
        if (ov > bv || (ov == bv && oi < bi)) { bv = ov; bi = oi; }
    }
    return bi;
}

// ================= K1: stage 1 (per-line MLP, LDS weights) -> c1 =================
extern "C" __global__ __launch_bounds__(256, 4)
void k_stage1(const float* __restrict__ x_in,
              const float* __restrict__ w1_0, const float* __restrict__ b1_0,
              const float* __restrict__ w1_1, const float* __restrict__ b1_1,
              const float* __restrict__ w1_2, const float* __restrict__ b1_2,
              int* __restrict__ c1out) {
    const int h = blockIdx.y;
    const int tid = threadIdx.x;
    const int p = tid >> 2;
    const int s = tid & 3;
    const int w = blockIdx.x * 64 + p;
    const bool valid = (w < WW);
    const int wc = valid ? w : (WW - 1);
    const int base = h * WW + wc;

    __shared__ __align__(16) float sW0[1024];
    __shared__ __align__(16) float sW1[1024];
    __shared__ __align__(16) float sW2[512];
    for (int tt = tid; tt < 1024; tt += 256) {
        int i = tt >> 5, o = tt & 31;
        sW0[tt] = w1_0[h * 1024 + o * 32 + i];
        sW1[tt] = w1_1[h * 1024 + o * 32 + i];
    }
    for (int tt = tid; tt < 512; tt += 256) {
        int i = tt >> 4, o = tt & 15;
        sW2[tt] = w1_2[h * 512 + o * 32 + i];
    }
    __syncthreads();

    float act[8], acc8[8], acc4[4];
#pragma unroll
    for (int ii = 0; ii < 8; ii++) act[ii] = x_in[(8 * s + ii) * HWSZ + base];
    cm4<32>(sW0, b1_0 + h * 32, s, act, acc8);
    wb_lrelu8(act, acc8);
    cm4<32>(sW1, b1_1 + h * 32, s, act, acc8);
    wb_lrelu8(act, acc8);
    cm4<16>(sW2, b1_2 + h * 16, s, act, acc4);
    const int i1 = argmax4(acc4, s);

    if (s == 0 && valid) c1out[base] = i1;
}

// ========= K2/K4: per-line counting sort of pixels by class -> perm =========
// perm[h*608 + sortedpos] = w. Any permutation works (pixels independent),
// so LDS-atomic ordering nondeterminism cannot affect d_out.
template <int NBINS>
__global__ __launch_bounds__(256)
void k_sort(const int* __restrict__ cls_in, int* __restrict__ perm, int clipmax) {
    const int h = blockIdx.x;
    const int tid = threadIdx.x;
    __shared__ int cls[WW];
    __shared__ int off[NBINS];
    __shared__ int hist[NBINS];
    for (int t = tid; t < NBINS; t += 256) hist[t] = 0;
    __syncthreads();
    for (int t = tid; t < WW; t += 256) {
        int v = cls_in[h * WW + t];
        v = min(max(v, 0), clipmax);
        cls[t] = v;
        atomicAdd(&hist[v], 1);
    }
    __syncthreads();
    if (tid == 0) {
        int run = 0;
        for (int i = 0; i < NBINS; i++) { off[i] = run; run += hist[i]; }
    }
    __syncthreads();
    for (int t = tid; t < WW; t += 256) {
        int pos = atomicAdd(&off[cls[t]], 1);
        perm[h * WW + pos] = t;
    }
}

// ========== K3: stage 2 in perm1 (class1-sorted) order -> inds12 ==========
extern "C" __global__ __launch_bounds__(256, 4)
void k_stage2(const float* __restrict__ x_in,
              const float* __restrict__ w2_0, const float* __restrict__ b2_0,
              const float* __restrict__ w2_1, const float* __restrict__ b2_1,
              const float* __restrict__ w2_2, const float* __restrict__ b2_2,
              const int* __restrict__ c1arr, const int* __restrict__ perm1,
              int* __restrict__ inds12out) {
    const int h = blockIdx.y;
    const int tid = threadIdx.x;
    const int s = tid & 3;
    int pos = blockIdx.x * 64 + (tid >> 2);
    pos = min(pos, WW - 1);                 // tail: duplicate last sorted pos
    const int p = perm1[h * WW + pos];
    const int base = h * WW + p;
    const int i1 = c1arr[base];

    float act[8], acc8[8], acc4[4];
#pragma unroll
    for (int ii = 0; ii < 8; ii++) act[ii] = x_in[(32 + 8 * s + ii) * HWSZ + base];
    const size_t idx2 = (size_t)h * 16 + (size_t)i1;
    cm4<32>(w2_0 + idx2 * 1024, b2_0 + idx2 * 32, s, act, acc8);
    wb_lrelu8(act, acc8);
    cm4<32>(w2_1 + idx2 * 1024, b2_1 + idx2 * 32, s, act, acc8);
    wb_lrelu8(act, acc8);
    cm4<16>(w2_2 + idx2 * 512, b2_2 + idx2 * 16, s, act, acc4);
    const int i2 = argmax4(acc4, s);

    if (s == 0) inds12out[base] = i1 * 12 + (i2 - 2);   // unclipped
}

// ===== K5: stage 3 + regressor in perm2 (class12-sorted) order -> out =====
extern "C" __global__ __launch_bounds__(256, 4)
void k_stage3(const float* __restrict__ x_in,
              const float* __restrict__ w3_0, const float* __restrict__ b3_0,
              const float* __restrict__ w3_1, const float* __restrict__ b3_1,
              const float* __restrict__ w3_2, const float* __restrict__ b3_2,
              const float* __restrict__ wr0, const float* __restrict__ br0,
              const float* __restrict__ wr1, const float* __restrict__ br1,
              const int* __restrict__ inds12arr, const int* __restrict__ perm2,
              float* __restrict__ out) {
    const int h = blockIdx.y;
    const int tid = threadIdx.x;
    const int s = tid & 3;
    int pos = blockIdx.x * 64 + (tid >> 2);
    pos = min(pos, WW - 1);
    const int p = perm2[h * WW + pos];
    const int base = h * WW + p;
    const int inds12 = inds12arr[base];
    const int c12 = min(max(inds12, 0), 191);
    const size_t idx3 = (size_t)h * 192 + (size_t)c12;

    float act[8], acc8[8], acc4[4];
#pragma unroll
    for (int ii = 0; ii < 8; ii++) act[ii] = x_in[(64 + 8 * s + ii) * HWSZ + base];
    cm4<32>(w3_0 + idx3 * 1024, b3_0 + idx3 * 32, s, act, acc8);
    wb_lrelu8(act, acc8);
    cm4<32>(w3_1 + idx3 * 1024, b3_1 + idx3 * 32, s, act, acc8);
    wb_lrelu8(act, acc8);
    cm4<16>(w3_2 + idx3 * 512, b3_2 + idx3 * 16, s, act, acc4);
    const int i3 = argmax4(acc4, s);

    const int inds123 = min(max(inds12 * 10 + (i3 - 3), 0), 1919);

#pragma unroll
    for (int ii = 0; ii < 8; ii++) act[ii] = x_in[(96 + 8 * s + ii) * HWSZ + base];
    const size_t idxs = (size_t)h * 384 + (size_t)(inds123 / 5);
    cm4<32>(wr0 + idxs * 1024, br0 + idxs * 32, s, act, acc8);
    wb_lrelu8(act, acc8);

    const size_t idxr = (size_t)h * 1920 + (size_t)inds123;
    const float* __restrict__ wr1r = wr1 + idxr * 32 + 8 * s;
    float4 wa = *reinterpret_cast<const float4*>(wr1r);
    float4 wb = *reinterpret_cast<const float4*>(wr1r + 4);
    float rpart = 0.0f;
    rpart = fmaf(act[0], wa.x, rpart); rpart = fmaf(act[1], wa.y, rpart);
    rpart = fmaf(act[2], wa.z, rpart); rpart = fmaf(act[3], wa.w, rpart);
    rpart = fmaf(act[4], wb.x, rpart); rpart = fmaf(act[5], wb.y, rpart);
    rpart = fmaf(act[6], wb.z, rpart); rpart = fmaf(act[7], wb.w, rpart);
    rpart += __shfl_xor(rpart, 1, 4);
    rpart += __shfl_xor(rpart, 2, 4);
    const float r = rpart + br1[idxr];

    if (s == 0) {
        float v = ((float)inds123 + r) * (1.0f / 1920.0f);
        out[base] = (v - 0.1f) * 1.25f;
    }
}

// =============== Fallback: proven monolithic kernel (R6, 135 us) ===============
extern "C" __global__ __launch_bounds__(256, 4)
void regressor_fused(const float* __restrict__ x_in,
                     const float* __restrict__ w1_0, const float* __restrict__ b1_0,
                     const float* __restrict__ w1_1, const float* __restrict__ b1_1,
                     const float* __restrict__ w1_2, const float* __restrict__ b1_2,
                     const float* __restrict__ w2_0, const float* __restrict__ b2_0,
                     const float* __restrict__ w2_1, const float* __restrict__ b2_1,
                     const float* __restrict__ w2_2, const float* __restrict__ b2_2,
                     const float* __restrict__ w3_0, const float* __restrict__ b3_0,
                     const float* __restrict__ w3_1, const float* __restrict__ b3_1,
                     const float* __restrict__ w3_2, const float* __restrict__ b3_2,
                     const float* __restrict__ wr0, const float* __restrict__ br0,
                     const float* __restrict__ wr1, const float* __restrict__ br1,
                     float* __restrict__ out) {
    const int h = blockIdx.y;
    const int tid = threadIdx.x;
    const int p = tid >> 2;
    const int s = tid & 3;
    const int w = blockIdx.x * 64 + p;
    const bool valid = (w < WW);
    const int wc = valid ? w : (WW - 1);
    const int base = h * WW + wc;

    __shared__ __align__(16) float sW0[1024];
    __shared__ __align__(16) float sW1[1024];
    __shared__ __align__(16) float sW2[512];
    for (int tt = tid; tt < 1024; tt += 256) {
        int i = tt >> 5, o = tt & 31;
        sW0[tt] = w1_0[h * 1024 + o * 32 + i];
        sW1[tt] = w1_1[h * 1024 + o * 32 + i];
    }
    for (int tt = tid; tt < 512; tt += 256) {
        int i = tt >> 4, o = tt & 15;
        sW2[tt] = w1_2[h * 512 + o * 32 + i];
    }
    __syncthreads();

    float act[8], acc8[8], acc4[4];
#pragma unroll
    for (int ii = 0; ii < 8; ii++) act[ii] = x_in[(8 * s + ii) * HWSZ + base];
    cm4<32>(sW0, b1_0 + h * 32, s, act, acc8);
    wb_lrelu8(act, acc8);
    cm4<32>(sW1, b1_1 + h * 32, s, act, acc8);
    wb_lrelu8(act, acc8);
    cm4<16>(sW2, b1_2 + h * 16, s, act, acc4);
    const int i1 = argmax4(acc4, s);

#pragma unroll
    for (int ii = 0; ii < 8; ii++) act[ii] = x_in[(32 + 8 * s + ii) * HWSZ + base];
    const size_t idx2 = (size_t)h * 16 + (size_t)i1;
    cm4<32>(w2_0 + idx2 * 1024, b2_0 + idx2 * 32, s, act, acc8);
    wb_lrelu8(act, acc8);
    cm4<32>(w2_1 + idx2 * 1024, b2_1 + idx2 * 32, s, act, acc8);
    wb_lrelu8(act, acc8);
    cm4<16>(w2_2 + idx2 * 512, b2_2 + idx2 * 16, s, act, acc4);
    const int i2 = argmax4(acc4, s);

    const int inds12 = i1 * 12 + (i2 - 2);
    const int c12 = min(max(inds12, 0), 191);
    const size_t idx3 = (size_t)h * 192 + (size_t)c12;

#pragma unroll
    for (int ii = 0; ii < 8; ii++) act[ii] = x_in[(64 + 8 * s + ii) * HWSZ + base];
    cm4<32>(w3_0 + idx3 * 1024, b3_0 + idx3 * 32, s, act, acc8);
    wb_lrelu8(act, acc8);
    cm4<32>(w3_1 + idx3 * 1024, b3_1 + idx3 * 32, s, act, acc8);
    wb_lrelu8(act, acc8);
    cm4<16>(w3_2 + idx3 * 512, b3_2 + idx3 * 16, s, act, acc4);
    const int i3 = argmax4(acc4, s);

    const int inds123 = min(max(inds12 * 10 + (i3 - 3), 0), 1919);

#pragma unroll
    for (int ii = 0; ii < 8; ii++) act[ii] = x_in[(96 + 8 * s + ii) * HWSZ + base];
    const size_t idxs = (size_t)h * 384 + (size_t)(inds123 / 5);
    cm4<32>(wr0 + idxs * 1024, br0 + idxs * 32, s, act, acc8);
    wb_lrelu8(act, acc8);

    const size_t idxr = (size_t)h * 1920 + (size_t)inds123;
    const float* __restrict__ wr1r = wr1 + idxr * 32 + 8 * s;
    float4 wa = *reinterpret_cast<const float4*>(wr1r);
    float4 wb = *reinterpret_cast<const float4*>(wr1r + 4);
    float rpart = 0.0f;
    rpart = fmaf(act[0], wa.x, rpart); rpart = fmaf(act[1], wa.y, rpart);
    rpart = fmaf(act[2], wa.z, rpart); rpart = fmaf(act[3], wa.w, rpart);
    rpart = fmaf(act[4], wb.x, rpart); rpart = fmaf(act[5], wb.y, rpart);
    rpart = fmaf(act[6], wb.z, rpart); rpart = fmaf(act[7], wb.w, rpart);
    rpart += __shfl_xor(rpart, 1, 4);
    rpart += __shfl_xor(rpart, 2, 4);
    const float r = rpart + br1[idxr];

    if (s == 0 && valid) {
        float v = ((float)inds123 + r) * (1.0f / 1920.0f);
        out[h * WW + w] = (v - 0.1f) * 1.25f;
    }
}

extern "C" void kernel_launch(void* const* d_in, const int* in_sizes, int n_in,
                              void* d_out, int out_size, void* d_ws, size_t ws_size,
                              hipStream_t stream) {
    const float* p[23];
    for (int i = 0; i < 23; i++) p[i] = (const float*)d_in[i];
    float* out = (float*)d_out;

    const size_t N = (size_t)HWSZ;
    const size_t need = 4 * N * sizeof(int);

    if (ws_size < need) {
        // Fallback: monolithic proven kernel.
        regressor_fused<<<dim3(10, HH), 256, 0, stream>>>(
            p[0], p[1], p[2], p[3], p[4], p[5], p[6],
            p[7], p[8], p[9], p[10], p[11], p[12],
            p[13], p[14], p[15], p[16], p[17], p[18],
            p[19], p[20], p[21], p[22], out);
        return;
    }

    int* c1 = (int*)d_ws;
    int* perm1 = c1 + N;
    int* inds12 = perm1 + N;
    int* perm2 = inds12 + N;

    dim3 gridMain(10, HH);
    k_stage1<<<gridMain, 256, 0, stream>>>(p[0], p[1], p[2], p[3], p[4], p[5], p[6], c1);
    k_sort<16><<<dim3(HH), 256, 0, stream>>>(c1, perm1, 15);
    k_stage2<<<gridMain, 256, 0, stream>>>(p[0], p[7], p[8], p[9], p[10], p[11], p[12],
                                           c1, perm1, inds12);
    k_sort<192><<<dim3(HH), 256, 0, stream>>>(inds12, perm2, 191);
    k_stage3<<<gridMain, 256, 0, stream>>>(p[0], p[13], p[14], p[15], p[16], p[17], p[18],
                                           p[19], p[20], p[21], p[22],
                                           inds12, perm2, out);
}